// Round 9
// baseline (135.122 us; speedup 1.0000x reference)
//
#include <hip/hip_runtime.h>
#include <hip/hip_bf16.h>
#include <stdint.h>
#include <math.h>

// ---------- types ----------
typedef __bf16 bf16;
typedef bf16  bf16x4  __attribute__((ext_vector_type(4)));
typedef bf16  bf16x8  __attribute__((ext_vector_type(8)));
typedef float floatx4 __attribute__((ext_vector_type(4)));

#define MFMA_16x16x32_BF16(a, b, c) \
  __builtin_amdgcn_mfma_f32_16x16x32_bf16((a), (b), (c), 0, 0, 0)

__device__ __forceinline__ int imin(int a, int b) { return a < b ? a : b; }
__device__ __forceinline__ int imax(int a, int b) { return a > b ? a : b; }

// async global->LDS, 16B per lane. LDS dest is wave-uniform base + lane*16.
__device__ __forceinline__ void load_lds16(const void* g, void* l) {
  __builtin_amdgcn_global_load_lds(
      (const __attribute__((address_space(1))) unsigned int*)g,
      (__attribute__((address_space(3))) unsigned int*)l, 16, 0, 0);
}

// ---------- constants ----------
// B=2, L=2048, D=1024, H=16, dh=64, WINDOW=256
#define LSEQ 2048
#define DMODEL 1024
#define NH 16
#define DH 64

// ============================================================
// 1) merged pack: blocks 0..4095 -> hidden fp32->bf16;
//    blocks 4096..7167 -> W^T bf16 transpose (32x32 tiles, z=q/k/v)
// ============================================================
__global__ void pack_all(const float4* __restrict__ x, uint16_t* __restrict__ y,
                         const float* __restrict__ Wq, const float* __restrict__ Wk,
                         const float* __restrict__ Wv, uint16_t* __restrict__ Wt) {
  const int bi = blockIdx.x;
  if (bi < 4096) {
    int i = bi * 256 + threadIdx.x;
    float4 f = x[i];
    bf16x4 v;
    v[0] = (bf16)f.x; v[1] = (bf16)f.y; v[2] = (bf16)f.z; v[3] = (bf16)f.w;
    *(bf16x4*)&y[(size_t)i * 4] = v;
    return;
  }
  __shared__ float tile[32][33];
  const int p = bi - 4096;              // 0..3071
  const int z = p >> 10;                // /1024
  const int rem = p & 1023;
  const int k0 = (rem >> 5) * 32, n0 = (rem & 31) * 32;
  const float* W = (z == 0) ? Wq : (z == 1) ? Wk : Wv;
  const int tx = threadIdx.x & 31, ty = threadIdx.x >> 5;  // 32x8
#pragma unroll
  for (int i = 0; i < 4; ++i)
    tile[ty + i * 8][tx] = W[(size_t)(k0 + ty + i * 8) * DMODEL + n0 + tx];
  __syncthreads();
  uint16_t* out = Wt + (size_t)z * DMODEL * DMODEL;
#pragma unroll
  for (int i = 0; i < 4; ++i)
    *(bf16*)&out[(size_t)(n0 + ty + i * 8) * DMODEL + k0 + tx] =
        (bf16)tile[tx][ty + i * 8];
}

// ============================================================
// 3) QKV GEMM, BK=32, DOUBLE-BUFFERED single-barrier K-loop, m-pinned
//    XCD swizzle, 3 blocks/CU (all 768 blocks co-resident).
//    Loop: barrier -> issue stage(i+1 -> buf^1) -> compute(buf). The
//    top-of-loop barrier drains a stage that had the whole previous
//    compute phase to complete -> staging latency hidden, not exposed.
//    z=0 -> q*0.125 [B,H,L,dh]; z=1 -> k; z=2 -> v TRANSPOSED [B,H,dh,L].
// ============================================================
__global__ __launch_bounds__(256, 3) void qkv_gemm(
    const uint16_t* __restrict__ A, const uint16_t* __restrict__ Wt,
    const float* __restrict__ bq, const float* __restrict__ bk,
    const float* __restrict__ bv,
    uint16_t* __restrict__ outq, uint16_t* __restrict__ outk,
    uint16_t* __restrict__ outvt) {
  // two 8192-elem staging buffers (A 4096 + B 4096 each); z=2 epilogue
  // reuses the whole array as a 128x136 C^T tile (17408 elems).
  __shared__ __attribute__((aligned(16))) uint16_t lds[17408];
  // m-pinned decode
  const int xcd = blockIdx.x & 7;
  const int i = blockIdx.x >> 3;        // 0..95
  const int m0 = (xcd * 4 + (i & 3)) * 128;
  const int rest = i >> 2;              // 0..23
  const int n0 = (rest & 7) * 128;
  const int z = rest >> 3;
  const uint16_t* Bt = Wt + (size_t)z * DMODEL * DMODEL;
  const float* bias = (z == 0) ? bq : (z == 1) ? bk : bv;

  const int t = threadIdx.x;
  const int lane = t & 63;
  const int wave = t >> 6;
  const int wm = (wave >> 1) * 64;
  const int wn = (wave & 1) * 64;
  const int col = lane & 15;
  const int quad = lane >> 4;

  floatx4 acc[4][4] = {};

  // stage k-slice kk (BK=32) into buffer bi: 1024 chunks of 16B, 4/thread.
  auto stage = [&](int kk, int bi) {
    const int k0 = kk * 32;
    uint16_t* base = &lds[bi * 8192];
#pragma unroll
    for (int c = 0; c < 4; ++c) {
      int chunk = t + c * 256;
      int cc = chunk & 511;
      int row = cc >> 2;
      int col16 = (cc & 3) ^ (row & 3);
      const uint16_t* g = (chunk < 512)
          ? A  + (size_t)(m0 + row) * DMODEL + k0 + col16 * 8
          : Bt + (size_t)(n0 + row) * DMODEL + k0 + col16 * 8;
      load_lds16(g, &base[chunk * 8]);
    }
  };

  stage(0, 0);
  for (int kk = 0; kk < 32; ++kk) {
    __syncthreads();   // drains stage(kk) (issued a full compute phase ago)
    if (kk < 31) stage(kk + 1, (kk + 1) & 1);
    const uint16_t* base = &lds[(kk & 1) * 8192];

    bf16x8 afrag[4], bfrag[4];
#pragma unroll
    for (int mi = 0; mi < 4; ++mi) {
      int r = wm + mi * 16 + col;
      afrag[mi] = *(const bf16x8*)&base[r * 32 + ((quad ^ (r & 3)) * 8)];
    }
#pragma unroll
    for (int nj = 0; nj < 4; ++nj) {
      int r = wn + nj * 16 + col;
      bfrag[nj] = *(const bf16x8*)&base[4096 + r * 32 + ((quad ^ (r & 3)) * 8)];
    }
#pragma unroll
    for (int mi = 0; mi < 4; ++mi)
#pragma unroll
      for (int nj = 0; nj < 4; ++nj)
        acc[mi][nj] = MFMA_16x16x32_BF16(afrag[mi], bfrag[nj], acc[mi][nj]);
  }

  // epilogue: C/D layout col=lane&15, row=quad*4+reg
  if (z != 2) {
    const float scale = (z == 0) ? 0.125f : 1.0f;  // fold 1/sqrt(dh) into q
    uint16_t* outp = (z == 0) ? outq : outk;
#pragma unroll
    for (int nj = 0; nj < 4; ++nj) {
      int gn = n0 + wn + nj * 16 + col;
      float bb = bias[gn];
      int h = gn >> 6, d = gn & 63;
#pragma unroll
      for (int mi = 0; mi < 4; ++mi) {
#pragma unroll
        for (int r = 0; r < 4; ++r) {
          int gm = m0 + wm + mi * 16 + quad * 4 + r;
          int b = gm >> 11, l = gm & 2047;
          *(bf16*)&outp[(((size_t)b * NH + h) * LSEQ + l) * DH + d] =
              (bf16)((acc[mi][nj][r] + bb) * scale);
        }
      }
    }
  } else {
    // V^T: transpose C through LDS (stride 136), coalesced 16B stores along l.
    __syncthreads();   // protect last k-iter's fragment reads before reuse
#pragma unroll
    for (int nj = 0; nj < 4; ++nj) {
      int n = wn + nj * 16 + col;
      float bb = bias[n0 + n];
#pragma unroll
      for (int mi = 0; mi < 4; ++mi)
#pragma unroll
        for (int r = 0; r < 4; ++r)
          *(bf16*)&lds[n * 136 + wm + mi * 16 + quad * 4 + r] =
              (bf16)(acc[mi][nj][r] + bb);
    }
    __syncthreads();
    const int n = t >> 1, mh = (t & 1) * 64;   // 2 threads per C column
    const int gn = n0 + n, d = gn & 63, h = gn >> 6;
    const int b = m0 >> 11, l0 = (m0 & 2047) + mh;
    uint16_t* dst = &outvt[(((size_t)b * NH + h) * DH + d) * LSEQ + l0];
    const uint16_t* src = &lds[n * 136 + mh];
#pragma unroll
    for (int j = 0; j < 8; ++j)
      *(bf16x8*)&dst[j * 8] = *(const bf16x8*)&src[j * 8];
  }
}

// ============================================================
// 4) windowed attention, block-cooperative LDS staging (R6 verified).
// ============================================================
__global__ __launch_bounds__(256, 4) void attn(
    const uint16_t* __restrict__ Q, const uint16_t* __restrict__ K,
    const uint16_t* __restrict__ Vt, float* __restrict__ out) {
  __shared__ __attribute__((aligned(16))) uint16_t kbuf[2][2048];  // 32 keys x 64 d
  __shared__ __attribute__((aligned(16))) uint16_t vbuf[2][2048];  // 64 d x 32 keys

  const int t = threadIdx.x;
  const int lane = t & 63;
  const int w = t >> 6;
  const int xcd = blockIdx.x & 7;
  const int slot = blockIdx.x >> 3;          // 0..127
  const int bh = xcd * 4 + (slot >> 5);      // 4 heads per XCD
  const int q0 = (slot & 31) * 64;           // block's query base
  const int q0w = q0 + w * 16;               // this wave's 16 queries
  const int b = bh >> 4, h = bh & 15;
  const uint16_t* Qp = Q + (size_t)bh * LSEQ * DH;
  const uint16_t* Kp = K + (size_t)bh * LSEQ * DH;
  const uint16_t* Vp = Vt + (size_t)bh * DH * LSEQ;
  const int col = lane & 15, quad = lane >> 4;

  bf16x8 qf0 = *(const bf16x8*)&Qp[(size_t)(q0w + col) * DH + quad * 8];
  bf16x8 qf1 = *(const bf16x8*)&Qp[(size_t)(q0w + col) * DH + 32 + quad * 8];

  bf16x8 ones;
#pragma unroll
  for (int u = 0; u < 8; ++u) ones[u] = (bf16)1.0f;

  const int c_start = (q0 < 256) ? ((256 - q0) >> 5) : 0;

  floatx4 o[4] = {};                    // O^T: d=nj*16+quad*4+r, q=col
  floatx4 lac = {0.f, 0.f, 0.f, 0.f};   // row sums (all regs equal l[q=col])

  auto stage = [&](int c, int bi) {
    const int kc = q0 - 256 + 32 * c;   // >= 0 by construction
    {
      int ci = w * 64 + lane;
      int row = ci >> 3, s16 = ci & 7;
      const uint16_t* g = Kp + (size_t)(kc + row) * DH + ((s16 ^ (row & 7)) * 8);
      load_lds16(g, &kbuf[bi][w * 512]);
    }
    {
      int ci = w * 64 + lane;
      int d = ci >> 2, s4 = ci & 3;
      const uint16_t* g = Vp + (size_t)d * LSEQ + kc + ((s4 ^ (d & 3)) * 8);
      load_lds16(g, &vbuf[bi][w * 512]);
    }
  };

  stage(c_start, c_start & 1);

  for (int c = c_start; c <= 9; ++c) {
    __syncthreads();                    // drains vmcnt: buf[c&1] ready
    if (c < 9) stage(c + 1, (c + 1) & 1);

    const int kc = q0 - 256 + 32 * c;
    const int hi = q0w + 15, lo = q0w - 255;
    if (kc <= hi && kc + 32 > lo) {
      const uint16_t* kb_ = kbuf[c & 1];
      const uint16_t* vb_ = vbuf[c & 1];

      // S^T = K . Q^T : A = K rows (m=key), B = Q (n=query)
      floatx4 sT[2] = {{0.f,0.f,0.f,0.f},{0.f,0.f,0.f,0.f}};
#pragma unroll
      for (int sub = 0; sub < 2; ++sub) {
        int r_ = sub * 16 + col;
        bf16x8 ka = *(const bf16x8*)&kb_[r_ * 64 + ((quad ^ (r_ & 7)) * 8)];
        bf16x8 kb2 = *(const bf16x8*)&kb_[r_ * 64 + (((4 + quad) ^ (r_ & 7)) * 8)];
        sT[sub] = MFMA_16x16x32_BF16(ka, qf0, sT[sub]);
        sT[sub] = MFMA_16x16x32_BF16(kb2, qf1, sT[sub]);
      }

      // per-query band mask + exp, pack P^T into B-frag.
      const bool needm = (kc < q0w - 240) | (kc + 31 > q0w);
      const int q = q0w + col;
      bf16x8 pb;
#pragma unroll
      for (int sub = 0; sub < 2; ++sub) {
#pragma unroll
        for (int r = 0; r < 4; ++r) {
          float v = sT[sub][r];
          if (needm) {
            int key = kc + sub * 16 + quad * 4 + r;
            v = ((key <= q) & (key > q - 256)) ? v : -INFINITY;  // exp(-inf)=0
          }
          pb[sub * 4 + r] = (bf16)__expf(v);
        }
      }

      // O^T += V^T . P^T  (A = V^T with the SAME k-mapping as pb)
#pragma unroll
      for (int nj = 0; nj < 4; ++nj) {
        int d = nj * 16 + col;
        bf16x4 vlo = *(const bf16x4*)&vb_[d * 32 + (((quad >> 1) ^ (d & 3)) * 8) + (quad & 1) * 4];
        bf16x4 vhi = *(const bf16x4*)&vb_[d * 32 + (((2 + (quad >> 1)) ^ (d & 3)) * 8) + (quad & 1) * 4];
        bf16x8 va;
#pragma unroll
        for (int u = 0; u < 4; ++u) { va[u] = vlo[u]; va[4 + u] = vhi[u]; }
        o[nj] = MFMA_16x16x32_BF16(va, pb, o[nj]);
      }
      lac = MFMA_16x16x32_BF16(ones, pb, lac);
    }
  }

  float rinv = 1.0f / lac[0];           // all lac regs equal l[q=col]
#pragma unroll
  for (int nj = 0; nj < 4; ++nj) {
    float4 v4;
    v4.x = o[nj][0] * rinv; v4.y = o[nj][1] * rinv;
    v4.z = o[nj][2] * rinv; v4.w = o[nj][3] * rinv;
    *(float4*)&out[((size_t)b * LSEQ + q0w + col) * DMODEL + h * DH + nj * 16 + quad * 4] = v4;
  }
}

// ============================================================
// launch
// ============================================================
extern "C" void kernel_launch(void* const* d_in, const int* in_sizes, int n_in,
                              void* d_out, int out_size, void* d_ws, size_t ws_size,
                              hipStream_t stream) {
  const float* hidden = (const float*)d_in[0];
  const float* Wq = (const float*)d_in[1];
  const float* bq = (const float*)d_in[2];
  const float* Wk = (const float*)d_in[3];
  const float* bk = (const float*)d_in[4];
  const float* Wv = (const float*)d_in[5];
  const float* bv = (const float*)d_in[6];
  float* out = (float*)d_out;

  // workspace layout (bytes): needs 38 MB
  char* ws = (char*)d_ws;
  uint16_t* hb  = (uint16_t*)(ws);                       // 8 MB  bf16 hidden
  uint16_t* Wt  = (uint16_t*)(ws + ((size_t)8  << 20));  // 6 MB  bf16 W^T x3
  uint16_t* qb  = (uint16_t*)(ws + ((size_t)14 << 20));  // 8 MB  q*0.125 [B,H,L,dh]
  uint16_t* kb  = (uint16_t*)(ws + ((size_t)22 << 20));  // 8 MB  k [B,H,L,dh]
  uint16_t* vtb = (uint16_t*)(ws + ((size_t)30 << 20));  // 8 MB  v^T [B,H,dh,L]

  pack_all<<<7168, 256, 0, stream>>>((const float4*)hidden, hb, Wq, Wk, Wv, Wt);
  qkv_gemm<<<768, 256, 0, stream>>>(hb, Wt, bq, bk, bv, qb, kb, vtb);
  attn<<<1024, 256, 0, stream>>>(qb, kb, vtb, out);
}

// Round 10
// 132.880 us; speedup vs baseline: 1.0169x; 1.0169x over previous
//
#include <hip/hip_runtime.h>
#include <hip/hip_bf16.h>
#include <stdint.h>
#include <math.h>

// ---------- types ----------
typedef __bf16 bf16;
typedef bf16  bf16x4  __attribute__((ext_vector_type(4)));
typedef bf16  bf16x8  __attribute__((ext_vector_type(8)));
typedef float floatx4 __attribute__((ext_vector_type(4)));

#define MFMA_16x16x32_BF16(a, b, c) \
  __builtin_amdgcn_mfma_f32_16x16x32_bf16((a), (b), (c), 0, 0, 0)

__device__ __forceinline__ int imin(int a, int b) { return a < b ? a : b; }
__device__ __forceinline__ int imax(int a, int b) { return a > b ? a : b; }

// async global->LDS, 16B per lane. LDS dest is wave-uniform base + lane*16.
__device__ __forceinline__ void load_lds16(const void* g, void* l) {
  __builtin_amdgcn_global_load_lds(
      (const __attribute__((address_space(1))) unsigned int*)g,
      (__attribute__((address_space(3))) unsigned int*)l, 16, 0, 0);
}

// ---------- constants ----------
// B=2, L=2048, D=1024, H=16, dh=64, WINDOW=256
#define LSEQ 2048
#define DMODEL 1024
#define NH 16
#define DH 64

// ============================================================
// 1) merged pack: blocks 0..4095 -> hidden fp32->bf16;
//    blocks 4096..7167 -> W^T bf16 transpose (32x32 tiles, z=q/k/v)
// ============================================================
__global__ void pack_all(const float4* __restrict__ x, uint16_t* __restrict__ y,
                         const float* __restrict__ Wq, const float* __restrict__ Wk,
                         const float* __restrict__ Wv, uint16_t* __restrict__ Wt) {
  const int bi = blockIdx.x;
  if (bi < 4096) {
    int i = bi * 256 + threadIdx.x;
    float4 f = x[i];
    bf16x4 v;
    v[0] = (bf16)f.x; v[1] = (bf16)f.y; v[2] = (bf16)f.z; v[3] = (bf16)f.w;
    *(bf16x4*)&y[(size_t)i * 4] = v;
    return;
  }
  __shared__ float tile[32][33];
  const int p = bi - 4096;              // 0..3071
  const int z = p >> 10;                // /1024
  const int rem = p & 1023;
  const int k0 = (rem >> 5) * 32, n0 = (rem & 31) * 32;
  const float* W = (z == 0) ? Wq : (z == 1) ? Wk : Wv;
  const int tx = threadIdx.x & 31, ty = threadIdx.x >> 5;  // 32x8
#pragma unroll
  for (int i = 0; i < 4; ++i)
    tile[ty + i * 8][tx] = W[(size_t)(k0 + ty + i * 8) * DMODEL + n0 + tx];
  __syncthreads();
  uint16_t* out = Wt + (size_t)z * DMODEL * DMODEL;
#pragma unroll
  for (int i = 0; i < 4; ++i)
    *(bf16*)&out[(size_t)(n0 + ty + i * 8) * DMODEL + k0 + tx] =
        (bf16)tile[tx][ty + i * 8];
}

// ============================================================
// 3) QKV GEMM, BK=32, double-buffered single-barrier K-loop, m-pinned
//    XCD swizzle, 3 blocks/CU.
//    z=0 -> q*0.125 [B,H,L,dh]; z=1 -> k; z=2 -> v TRANSPOSED [B,H,dh,L]
//    with keys PERMUTED within each aligned 32-key panel to match the attn
//    PV MFMA k-mapping: key kk -> pos ((kk>>2)&3)*8 + ((kk>>4)&1)*4 + (kk&3),
//    so attn can read V A-frags as single b128s.
// ============================================================
__global__ __launch_bounds__(256, 3) void qkv_gemm(
    const uint16_t* __restrict__ A, const uint16_t* __restrict__ Wt,
    const float* __restrict__ bq, const float* __restrict__ bk,
    const float* __restrict__ bv,
    uint16_t* __restrict__ outq, uint16_t* __restrict__ outk,
    uint16_t* __restrict__ outvt) {
  // two 8192-elem staging buffers (A 4096 + B 4096 each); z=2 epilogue
  // reuses the whole array as a 128x136 C^T tile (17408 elems).
  __shared__ __attribute__((aligned(16))) uint16_t lds[17408];
  // m-pinned decode
  const int xcd = blockIdx.x & 7;
  const int i = blockIdx.x >> 3;        // 0..95
  const int m0 = (xcd * 4 + (i & 3)) * 128;
  const int rest = i >> 2;              // 0..23
  const int n0 = (rest & 7) * 128;
  const int z = rest >> 3;
  const uint16_t* Bt = Wt + (size_t)z * DMODEL * DMODEL;
  const float* bias = (z == 0) ? bq : (z == 1) ? bk : bv;

  const int t = threadIdx.x;
  const int lane = t & 63;
  const int wave = t >> 6;
  const int wm = (wave >> 1) * 64;
  const int wn = (wave & 1) * 64;
  const int col = lane & 15;
  const int quad = lane >> 4;

  floatx4 acc[4][4] = {};

  // stage k-slice kk (BK=32) into buffer bi: 1024 chunks of 16B, 4/thread.
  auto stage = [&](int kk, int bi) {
    const int k0 = kk * 32;
    uint16_t* base = &lds[bi * 8192];
#pragma unroll
    for (int c = 0; c < 4; ++c) {
      int chunk = t + c * 256;
      int cc = chunk & 511;
      int row = cc >> 2;
      int col16 = (cc & 3) ^ (row & 3);
      const uint16_t* g = (chunk < 512)
          ? A  + (size_t)(m0 + row) * DMODEL + k0 + col16 * 8
          : Bt + (size_t)(n0 + row) * DMODEL + k0 + col16 * 8;
      load_lds16(g, &base[chunk * 8]);
    }
  };

  stage(0, 0);
  for (int kk = 0; kk < 32; ++kk) {
    __syncthreads();   // drains stage(kk) (issued a full compute phase ago)
    if (kk < 31) stage(kk + 1, (kk + 1) & 1);
    const uint16_t* base = &lds[(kk & 1) * 8192];

    bf16x8 afrag[4], bfrag[4];
#pragma unroll
    for (int mi = 0; mi < 4; ++mi) {
      int r = wm + mi * 16 + col;
      afrag[mi] = *(const bf16x8*)&base[r * 32 + ((quad ^ (r & 3)) * 8)];
    }
#pragma unroll
    for (int nj = 0; nj < 4; ++nj) {
      int r = wn + nj * 16 + col;
      bfrag[nj] = *(const bf16x8*)&base[4096 + r * 32 + ((quad ^ (r & 3)) * 8)];
    }
#pragma unroll
    for (int mi = 0; mi < 4; ++mi)
#pragma unroll
      for (int nj = 0; nj < 4; ++nj)
        acc[mi][nj] = MFMA_16x16x32_BF16(afrag[mi], bfrag[nj], acc[mi][nj]);
  }

  // epilogue: C/D layout col=lane&15, row=quad*4+reg
  if (z != 2) {
    const float scale = (z == 0) ? 0.125f : 1.0f;  // fold 1/sqrt(dh) into q
    uint16_t* outp = (z == 0) ? outq : outk;
#pragma unroll
    for (int nj = 0; nj < 4; ++nj) {
      int gn = n0 + wn + nj * 16 + col;
      float bb = bias[gn];
      int h = gn >> 6, d = gn & 63;
#pragma unroll
      for (int mi = 0; mi < 4; ++mi) {
#pragma unroll
        for (int r = 0; r < 4; ++r) {
          int gm = m0 + wm + mi * 16 + quad * 4 + r;
          int b = gm >> 11, l = gm & 2047;
          *(bf16*)&outp[(((size_t)b * NH + h) * LSEQ + l) * DH + d] =
              (bf16)((acc[mi][nj][r] + bb) * scale);
        }
      }
    }
  } else {
    // V^T: transpose C through LDS (stride 136) with the 32-key-panel
    // permutation baked in (m = l; groups of 4 stay contiguous since
    // mb = wm+mi*16+quad*4 is a multiple of 4), then coalesced 16B stores.
    __syncthreads();   // protect last k-iter's fragment reads before reuse
#pragma unroll
    for (int nj = 0; nj < 4; ++nj) {
      int n = wn + nj * 16 + col;
      float bb = bias[n0 + n];
#pragma unroll
      for (int mi = 0; mi < 4; ++mi) {
        int mb = wm + mi * 16 + quad * 4;
        int pp = (mb & ~31) | (((mb >> 2) & 3) << 3) | (((mb >> 4) & 1) << 2);
#pragma unroll
        for (int r = 0; r < 4; ++r)
          *(bf16*)&lds[n * 136 + pp + r] = (bf16)(acc[mi][nj][r] + bb);
      }
    }
    __syncthreads();
    const int n = t >> 1, mh = (t & 1) * 64;   // 2 threads per C column
    const int gn = n0 + n, d = gn & 63, h = gn >> 6;
    const int b = m0 >> 11, l0 = (m0 & 2047) + mh;
    uint16_t* dst = &outvt[(((size_t)b * NH + h) * DH + d) * LSEQ + l0];
    const uint16_t* src = &lds[n * 136 + mh];
#pragma unroll
    for (int j = 0; j < 8; ++j)
      *(bf16x8*)&dst[j * 8] = *(const bf16x8*)&src[j * 8];
  }
}

// ============================================================
// 4) windowed attention, block-cooperative LDS staging (R6 verified).
//    V^T global layout is pre-permuted per 32-key panel -> each PV A-frag
//    is ONE ds_read_b128 (same XOR bank-swizzle pattern as the K reads).
// ============================================================
__global__ __launch_bounds__(256, 4) void attn(
    const uint16_t* __restrict__ Q, const uint16_t* __restrict__ K,
    const uint16_t* __restrict__ Vt, float* __restrict__ out) {
  __shared__ __attribute__((aligned(16))) uint16_t kbuf[2][2048];  // 32 keys x 64 d
  __shared__ __attribute__((aligned(16))) uint16_t vbuf[2][2048];  // 64 d x 32 keys (permuted)

  const int t = threadIdx.x;
  const int lane = t & 63;
  const int w = t >> 6;
  const int xcd = blockIdx.x & 7;
  const int slot = blockIdx.x >> 3;          // 0..127
  const int bh = xcd * 4 + (slot >> 5);      // 4 heads per XCD
  const int q0 = (slot & 31) * 64;           // block's query base
  const int q0w = q0 + w * 16;               // this wave's 16 queries
  const int b = bh >> 4, h = bh & 15;
  const uint16_t* Qp = Q + (size_t)bh * LSEQ * DH;
  const uint16_t* Kp = K + (size_t)bh * LSEQ * DH;
  const uint16_t* Vp = Vt + (size_t)bh * DH * LSEQ;
  const int col = lane & 15, quad = lane >> 4;

  bf16x8 qf0 = *(const bf16x8*)&Qp[(size_t)(q0w + col) * DH + quad * 8];
  bf16x8 qf1 = *(const bf16x8*)&Qp[(size_t)(q0w + col) * DH + 32 + quad * 8];

  bf16x8 ones;
#pragma unroll
  for (int u = 0; u < 8; ++u) ones[u] = (bf16)1.0f;

  const int c_start = (q0 < 256) ? ((256 - q0) >> 5) : 0;

  floatx4 o[4] = {};                    // O^T: d=nj*16+quad*4+r, q=col
  floatx4 lac = {0.f, 0.f, 0.f, 0.f};   // row sums (all regs equal l[q=col])

  auto stage = [&](int c, int bi) {
    const int kc = q0 - 256 + 32 * c;   // >= 0 by construction
    {
      int ci = w * 64 + lane;
      int row = ci >> 3, s16 = ci & 7;
      const uint16_t* g = Kp + (size_t)(kc + row) * DH + ((s16 ^ (row & 7)) * 8);
      load_lds16(g, &kbuf[bi][w * 512]);
    }
    {
      int ci = w * 64 + lane;
      int d = ci >> 2, s4 = ci & 3;
      const uint16_t* g = Vp + (size_t)d * LSEQ + kc + ((s4 ^ (d & 3)) * 8);
      load_lds16(g, &vbuf[bi][w * 512]);
    }
  };

  stage(c_start, c_start & 1);

  for (int c = c_start; c <= 9; ++c) {
    __syncthreads();                    // drains vmcnt: buf[c&1] ready
    if (c < 9) stage(c + 1, (c + 1) & 1);

    const int kc = q0 - 256 + 32 * c;
    const int hi = q0w + 15, lo = q0w - 255;
    if (kc <= hi && kc + 32 > lo) {
      const uint16_t* kb_ = kbuf[c & 1];
      const uint16_t* vb_ = vbuf[c & 1];

      // S^T = K . Q^T : A = K rows (m=key), B = Q (n=query)
      floatx4 sT[2] = {{0.f,0.f,0.f,0.f},{0.f,0.f,0.f,0.f}};
#pragma unroll
      for (int sub = 0; sub < 2; ++sub) {
        int r_ = sub * 16 + col;
        bf16x8 ka = *(const bf16x8*)&kb_[r_ * 64 + ((quad ^ (r_ & 7)) * 8)];
        bf16x8 kb2 = *(const bf16x8*)&kb_[r_ * 64 + (((4 + quad) ^ (r_ & 7)) * 8)];
        sT[sub] = MFMA_16x16x32_BF16(ka, qf0, sT[sub]);
        sT[sub] = MFMA_16x16x32_BF16(kb2, qf1, sT[sub]);
      }

      // per-query band mask + exp, pack P^T into B-frag.
      const bool needm = (kc < q0w - 240) | (kc + 31 > q0w);
      const int q = q0w + col;
      bf16x8 pb;
#pragma unroll
      for (int sub = 0; sub < 2; ++sub) {
#pragma unroll
        for (int r = 0; r < 4; ++r) {
          float v = sT[sub][r];
          if (needm) {
            int key = kc + sub * 16 + quad * 4 + r;
            v = ((key <= q) & (key > q - 256)) ? v : -INFINITY;  // exp(-inf)=0
          }
          pb[sub * 4 + r] = (bf16)__expf(v);
        }
      }

      // O^T += V^T . P^T — A-frag is one b128 (global layout pre-permuted)
#pragma unroll
      for (int nj = 0; nj < 4; ++nj) {
        int d = nj * 16 + col;
        bf16x8 va = *(const bf16x8*)&vb_[d * 32 + ((quad ^ (d & 3)) * 8)];
        o[nj] = MFMA_16x16x32_BF16(va, pb, o[nj]);
      }
      lac = MFMA_16x16x32_BF16(ones, pb, lac);
    }
  }

  float rinv = 1.0f / lac[0];           // all lac regs equal l[q=col]
#pragma unroll
  for (int nj = 0; nj < 4; ++nj) {
    float4 v4;
    v4.x = o[nj][0] * rinv; v4.y = o[nj][1] * rinv;
    v4.z = o[nj][2] * rinv; v4.w = o[nj][3] * rinv;
    *(float4*)&out[((size_t)b * LSEQ + q0w + col) * DMODEL + h * DH + nj * 16 + quad * 4] = v4;
  }
}

// ============================================================
// launch
// ============================================================
extern "C" void kernel_launch(void* const* d_in, const int* in_sizes, int n_in,
                              void* d_out, int out_size, void* d_ws, size_t ws_size,
                              hipStream_t stream) {
  const float* hidden = (const float*)d_in[0];
  const float* Wq = (const float*)d_in[1];
  const float* bq = (const float*)d_in[2];
  const float* Wk = (const float*)d_in[3];
  const float* bk = (const float*)d_in[4];
  const float* Wv = (const float*)d_in[5];
  const float* bv = (const float*)d_in[6];
  float* out = (float*)d_out;

  // workspace layout (bytes): needs 38 MB
  char* ws = (char*)d_ws;
  uint16_t* hb  = (uint16_t*)(ws);                       // 8 MB  bf16 hidden
  uint16_t* Wt  = (uint16_t*)(ws + ((size_t)8  << 20));  // 6 MB  bf16 W^T x3
  uint16_t* qb  = (uint16_t*)(ws + ((size_t)14 << 20));  // 8 MB  q*0.125 [B,H,L,dh]
  uint16_t* kb  = (uint16_t*)(ws + ((size_t)22 << 20));  // 8 MB  k [B,H,L,dh]
  uint16_t* vtb = (uint16_t*)(ws + ((size_t)30 << 20));  // 8 MB  v^T perm [B,H,dh,L]

  pack_all<<<7168, 256, 0, stream>>>((const float4*)hidden, hb, Wq, Wk, Wv, Wt);
  qkv_gemm<<<768, 256, 0, stream>>>(hb, Wt, bq, bk, bv, qb, kb, vtb);
  attn<<<1024, 256, 0, stream>>>(qb, kb, vtb, out);
}

// Round 11
// 131.821 us; speedup vs baseline: 1.0250x; 1.0080x over previous
//
#include <hip/hip_runtime.h>
#include <hip/hip_bf16.h>
#include <stdint.h>
#include <math.h>

// ---------- types ----------
typedef __bf16 bf16;
typedef bf16  bf16x4  __attribute__((ext_vector_type(4)));
typedef bf16  bf16x8  __attribute__((ext_vector_type(8)));
typedef float floatx4 __attribute__((ext_vector_type(4)));

#define MFMA_16x16x32_BF16(a, b, c) \
  __builtin_amdgcn_mfma_f32_16x16x32_bf16((a), (b), (c), 0, 0, 0)

__device__ __forceinline__ int imin(int a, int b) { return a < b ? a : b; }
__device__ __forceinline__ int imax(int a, int b) { return a > b ? a : b; }

// async global->LDS, 16B per lane. LDS dest is wave-uniform base + lane*16.
__device__ __forceinline__ void load_lds16(const void* g, void* l) {
  __builtin_amdgcn_global_load_lds(
      (const __attribute__((address_space(1))) unsigned int*)g,
      (__attribute__((address_space(3))) unsigned int*)l, 16, 0, 0);
}

// ---------- constants ----------
// B=2, L=2048, D=1024, H=16, dh=64, WINDOW=256
#define LSEQ 2048
#define DMODEL 1024
#define NH 16
#define DH 64

// ============================================================
// 1) merged pack: blocks 0..4095 -> hidden fp32->bf16;
//    blocks 4096..7167 -> W^T bf16 transpose (32x32 tiles, z=q/k/v)
// ============================================================
__global__ void pack_all(const float4* __restrict__ x, uint16_t* __restrict__ y,
                         const float* __restrict__ Wq, const float* __restrict__ Wk,
                         const float* __restrict__ Wv, uint16_t* __restrict__ Wt) {
  const int bi = blockIdx.x;
  if (bi < 4096) {
    int i = bi * 256 + threadIdx.x;
    float4 f = x[i];
    bf16x4 v;
    v[0] = (bf16)f.x; v[1] = (bf16)f.y; v[2] = (bf16)f.z; v[3] = (bf16)f.w;
    *(bf16x4*)&y[(size_t)i * 4] = v;
    return;
  }
  __shared__ float tile[32][33];
  const int p = bi - 4096;              // 0..3071
  const int z = p >> 10;                // /1024
  const int rem = p & 1023;
  const int k0 = (rem >> 5) * 32, n0 = (rem & 31) * 32;
  const float* W = (z == 0) ? Wq : (z == 1) ? Wk : Wv;
  const int tx = threadIdx.x & 31, ty = threadIdx.x >> 5;  // 32x8
#pragma unroll
  for (int i = 0; i < 4; ++i)
    tile[ty + i * 8][tx] = W[(size_t)(k0 + ty + i * 8) * DMODEL + n0 + tx];
  __syncthreads();
  uint16_t* out = Wt + (size_t)z * DMODEL * DMODEL;
#pragma unroll
  for (int i = 0; i < 4; ++i)
    *(bf16*)&out[(size_t)(n0 + ty + i * 8) * DMODEL + k0 + tx] =
        (bf16)tile[tx][ty + i * 8];
}

// ============================================================
// 3) QKV GEMM, BK=32, double-buffered single-barrier K-loop, m-pinned
//    XCD swizzle, 3 blocks/CU (R10 verified, at the m97-structure plateau).
//    z=0 -> q*0.125 [B,H,L,dh]; z=1 -> k; z=2 -> v TRANSPOSED [B,H,dh,L]
//    with keys permuted within each aligned 32-key panel:
//    kk -> ((kk>>2)&3)*8 + ((kk>>4)&1)*4 + (kk&3)  (attn PV A-frag = 1 b128).
// ============================================================
__global__ __launch_bounds__(256, 3) void qkv_gemm(
    const uint16_t* __restrict__ A, const uint16_t* __restrict__ Wt,
    const float* __restrict__ bq, const float* __restrict__ bk,
    const float* __restrict__ bv,
    uint16_t* __restrict__ outq, uint16_t* __restrict__ outk,
    uint16_t* __restrict__ outvt) {
  __shared__ __attribute__((aligned(16))) uint16_t lds[17408];
  // m-pinned decode
  const int xcd = blockIdx.x & 7;
  const int i = blockIdx.x >> 3;        // 0..95
  const int m0 = (xcd * 4 + (i & 3)) * 128;
  const int rest = i >> 2;              // 0..23
  const int n0 = (rest & 7) * 128;
  const int z = rest >> 3;
  const uint16_t* Bt = Wt + (size_t)z * DMODEL * DMODEL;
  const float* bias = (z == 0) ? bq : (z == 1) ? bk : bv;

  const int t = threadIdx.x;
  const int lane = t & 63;
  const int wave = t >> 6;
  const int wm = (wave >> 1) * 64;
  const int wn = (wave & 1) * 64;
  const int col = lane & 15;
  const int quad = lane >> 4;

  floatx4 acc[4][4] = {};

  auto stage = [&](int kk, int bi) {
    const int k0 = kk * 32;
    uint16_t* base = &lds[bi * 8192];
#pragma unroll
    for (int c = 0; c < 4; ++c) {
      int chunk = t + c * 256;
      int cc = chunk & 511;
      int row = cc >> 2;
      int col16 = (cc & 3) ^ (row & 3);
      const uint16_t* g = (chunk < 512)
          ? A  + (size_t)(m0 + row) * DMODEL + k0 + col16 * 8
          : Bt + (size_t)(n0 + row) * DMODEL + k0 + col16 * 8;
      load_lds16(g, &base[chunk * 8]);
    }
  };

  stage(0, 0);
  for (int kk = 0; kk < 32; ++kk) {
    __syncthreads();   // drains stage(kk) (issued a full compute phase ago)
    if (kk < 31) stage(kk + 1, (kk + 1) & 1);
    const uint16_t* base = &lds[(kk & 1) * 8192];

    bf16x8 afrag[4], bfrag[4];
#pragma unroll
    for (int mi = 0; mi < 4; ++mi) {
      int r = wm + mi * 16 + col;
      afrag[mi] = *(const bf16x8*)&base[r * 32 + ((quad ^ (r & 3)) * 8)];
    }
#pragma unroll
    for (int nj = 0; nj < 4; ++nj) {
      int r = wn + nj * 16 + col;
      bfrag[nj] = *(const bf16x8*)&base[4096 + r * 32 + ((quad ^ (r & 3)) * 8)];
    }
#pragma unroll
    for (int mi = 0; mi < 4; ++mi)
#pragma unroll
      for (int nj = 0; nj < 4; ++nj)
        acc[mi][nj] = MFMA_16x16x32_BF16(afrag[mi], bfrag[nj], acc[mi][nj]);
  }

  // epilogue: C/D layout col=lane&15, row=quad*4+reg
  if (z != 2) {
    const float scale = (z == 0) ? 0.125f : 1.0f;  // fold 1/sqrt(dh) into q
    uint16_t* outp = (z == 0) ? outq : outk;
#pragma unroll
    for (int nj = 0; nj < 4; ++nj) {
      int gn = n0 + wn + nj * 16 + col;
      float bb = bias[gn];
      int h = gn >> 6, d = gn & 63;
#pragma unroll
      for (int mi = 0; mi < 4; ++mi) {
#pragma unroll
        for (int r = 0; r < 4; ++r) {
          int gm = m0 + wm + mi * 16 + quad * 4 + r;
          int b = gm >> 11, l = gm & 2047;
          *(bf16*)&outp[(((size_t)b * NH + h) * LSEQ + l) * DH + d] =
              (bf16)((acc[mi][nj][r] + bb) * scale);
        }
      }
    }
  } else {
    // V^T: transpose C through LDS (stride 136) with the 32-key-panel
    // permutation baked in, then coalesced 16B stores along l.
    __syncthreads();   // protect last k-iter's fragment reads before reuse
#pragma unroll
    for (int nj = 0; nj < 4; ++nj) {
      int n = wn + nj * 16 + col;
      float bb = bias[n0 + n];
#pragma unroll
      for (int mi = 0; mi < 4; ++mi) {
        int mb = wm + mi * 16 + quad * 4;
        int pp = (mb & ~31) | (((mb >> 2) & 3) << 3) | (((mb >> 4) & 1) << 2);
#pragma unroll
        for (int r = 0; r < 4; ++r)
          *(bf16*)&lds[n * 136 + pp + r] = (bf16)(acc[mi][nj][r] + bb);
      }
    }
    __syncthreads();
    const int n = t >> 1, mh = (t & 1) * 64;   // 2 threads per C column
    const int gn = n0 + n, d = gn & 63, h = gn >> 6;
    const int b = m0 >> 11, l0 = (m0 & 2047) + mh;
    uint16_t* dst = &outvt[(((size_t)b * NH + h) * DH + d) * LSEQ + l0];
    const uint16_t* src = &lds[n * 136 + mh];
#pragma unroll
    for (int j = 0; j < 8; ++j)
      *(bf16x8*)&dst[j * 8] = *(const bf16x8*)&src[j * 8];
  }
}

// ============================================================
// 4) windowed attention, block-cooperative LDS staging, 64-KEY CHUNKS:
//    5 chunks instead of 10 -> half the barriers/stage calls, 2x longer
//    compute phase per barrier (fully hides the prefetched L2 latency).
//    K tile 64x64, V^T tile 64d x 64keys (two permuted 32-key panels),
//    both double-buffered (32 KB LDS, 4 blocks/CU).
// ============================================================
__global__ __launch_bounds__(256, 4) void attn(
    const uint16_t* __restrict__ Q, const uint16_t* __restrict__ K,
    const uint16_t* __restrict__ Vt, float* __restrict__ out) {
  __shared__ __attribute__((aligned(16))) uint16_t kbuf[2][4096];  // 64 keys x 64 d
  __shared__ __attribute__((aligned(16))) uint16_t vbuf[2][4096];  // 64 d x 64 keys

  const int t = threadIdx.x;
  const int lane = t & 63;
  const int w = t >> 6;
  const int xcd = blockIdx.x & 7;
  const int slot = blockIdx.x >> 3;          // 0..127
  const int bh = xcd * 4 + (slot >> 5);      // 4 heads per XCD
  const int q0 = (slot & 31) * 64;           // block's query base
  const int q0w = q0 + w * 16;               // this wave's 16 queries
  const int b = bh >> 4, h = bh & 15;
  const uint16_t* Qp = Q + (size_t)bh * LSEQ * DH;
  const uint16_t* Kp = K + (size_t)bh * LSEQ * DH;
  const uint16_t* Vp = Vt + (size_t)bh * DH * LSEQ;
  const int col = lane & 15, quad = lane >> 4;

  bf16x8 qf0 = *(const bf16x8*)&Qp[(size_t)(q0w + col) * DH + quad * 8];
  bf16x8 qf1 = *(const bf16x8*)&Qp[(size_t)(q0w + col) * DH + 32 + quad * 8];

  bf16x8 ones;
#pragma unroll
  for (int u = 0; u < 8; ++u) ones[u] = (bf16)1.0f;

  // chunk c covers keys [q0-256+64c, +64); skip fully-negative chunks.
  const int c_start = (q0 < 256) ? ((256 - q0) >> 6) : 0;

  floatx4 o[4] = {};                    // O^T: d=nj*16+quad*4+r, q=col
  floatx4 lac = {0.f, 0.f, 0.f, 0.f};   // row sums (all regs equal l[q=col])

  // stage chunk c (64 keys) into buffer bi: K 512 + V 512 16B-chunks,
  // 2 each per thread; per-wave bases are wave-uniform.
  auto stage = [&](int c, int bi) {
    const int kc = q0 - 256 + 64 * c;   // >= 0 by construction
    int ci = w * 64 + lane;
    {
      int row = ci >> 3, s = ci & 7;    // rows 0..31
      const uint16_t* g = Kp + (size_t)(kc + row) * DH + ((s ^ (row & 7)) * 8);
      load_lds16(g, &kbuf[bi][w * 512]);
      int row2 = row + 32;              // rows 32..63
      const uint16_t* g2 = Kp + (size_t)(kc + row2) * DH + ((s ^ (row2 & 7)) * 8);
      load_lds16(g2, &kbuf[bi][2048 + w * 512]);
    }
    {
      int d = ci >> 3, s = ci & 7;      // d 0..31
      const uint16_t* g = Vp + (size_t)d * LSEQ + kc + ((s ^ (d & 7)) * 8);
      load_lds16(g, &vbuf[bi][w * 512]);
      int d2 = d + 32;                  // d 32..63
      const uint16_t* g2 = Vp + (size_t)d2 * LSEQ + kc + ((s ^ (d2 & 7)) * 8);
      load_lds16(g2, &vbuf[bi][2048 + w * 512]);
    }
  };

  stage(c_start, c_start & 1);

  for (int c = c_start; c <= 4; ++c) {
    __syncthreads();                    // drains vmcnt: buf[c&1] ready
    if (c < 4) stage(c + 1, (c + 1) & 1);

    const int kc = q0 - 256 + 64 * c;
    const int hi = q0w + 15, lo = q0w - 255;
    if (kc <= hi && kc + 64 > lo) {     // chunk intersects this wave's window
      const uint16_t* kb_ = kbuf[c & 1];
      const uint16_t* vb_ = vbuf[c & 1];

      // S^T = K . Q^T : A = K rows (m=key), B = Q (n=query); 4 key-subtiles
      floatx4 sT[4] = {{0,0,0,0},{0,0,0,0},{0,0,0,0},{0,0,0,0}};
#pragma unroll
      for (int sub = 0; sub < 4; ++sub) {
        int r_ = sub * 16 + col;        // key row in 64-row tile
        bf16x8 ka  = *(const bf16x8*)&kb_[r_ * 64 + ((quad ^ (r_ & 7)) * 8)];
        bf16x8 kb2 = *(const bf16x8*)&kb_[r_ * 64 + (((4 + quad) ^ (r_ & 7)) * 8)];
        sT[sub] = MFMA_16x16x32_BF16(ka, qf0, sT[sub]);
        sT[sub] = MFMA_16x16x32_BF16(kb2, qf1, sT[sub]);
      }

      // per-query band mask + exp; pack two P^T B-frags (one per 32-key panel)
      // panel-local mapping: key(quad,j) = (j>>2)*16 + quad*4 + (j&3).
      const bool needm = (kc < q0w - 240) | (kc + 63 > q0w);
      const int q = q0w + col;
      bf16x8 pb[2];
#pragma unroll
      for (int sel = 0; sel < 2; ++sel) {
#pragma unroll
        for (int sp = 0; sp < 2; ++sp) {
#pragma unroll
          for (int r = 0; r < 4; ++r) {
            float v = sT[sel * 2 + sp][r];
            if (needm) {
              int key = kc + sel * 32 + sp * 16 + quad * 4 + r;
              v = ((key <= q) & (key > q - 256)) ? v : -INFINITY;  // exp(-inf)=0
            }
            pb[sel][sp * 4 + r] = (bf16)__expf(v);
          }
        }
      }

      // O^T += V^T . P^T — one b128 A-frag per (nj, panel)
#pragma unroll
      for (int nj = 0; nj < 4; ++nj) {
        int d = nj * 16 + col;
        bf16x8 va0 = *(const bf16x8*)&vb_[d * 64 + ((quad ^ (d & 7)) * 8)];
        bf16x8 va1 = *(const bf16x8*)&vb_[d * 64 + (((4 + quad) ^ (d & 7)) * 8)];
        o[nj] = MFMA_16x16x32_BF16(va0, pb[0], o[nj]);
        o[nj] = MFMA_16x16x32_BF16(va1, pb[1], o[nj]);
      }
      lac = MFMA_16x16x32_BF16(ones, pb[0], lac);
      lac = MFMA_16x16x32_BF16(ones, pb[1], lac);
    }
  }

  float rinv = 1.0f / lac[0];           // all lac regs equal l[q=col]
#pragma unroll
  for (int nj = 0; nj < 4; ++nj) {
    float4 v4;
    v4.x = o[nj][0] * rinv; v4.y = o[nj][1] * rinv;
    v4.z = o[nj][2] * rinv; v4.w = o[nj][3] * rinv;
    *(float4*)&out[((size_t)b * LSEQ + q0w + col) * DMODEL + h * DH + nj * 16 + quad * 4] = v4;
  }
}

// ============================================================
// launch
// ============================================================
extern "C" void kernel_launch(void* const* d_in, const int* in_sizes, int n_in,
                              void* d_out, int out_size, void* d_ws, size_t ws_size,
                              hipStream_t stream) {
  const float* hidden = (const float*)d_in[0];
  const float* Wq = (const float*)d_in[1];
  const float* bq = (const float*)d_in[2];
  const float* Wk = (const float*)d_in[3];
  const float* bk = (const float*)d_in[4];
  const float* Wv = (const float*)d_in[5];
  const float* bv = (const float*)d_in[6];
  float* out = (float*)d_out;

  // workspace layout (bytes): needs 38 MB
  char* ws = (char*)d_ws;
  uint16_t* hb  = (uint16_t*)(ws);                       // 8 MB  bf16 hidden
  uint16_t* Wt  = (uint16_t*)(ws + ((size_t)8  << 20));  // 6 MB  bf16 W^T x3
  uint16_t* qb  = (uint16_t*)(ws + ((size_t)14 << 20));  // 8 MB  q*0.125 [B,H,L,dh]
  uint16_t* kb  = (uint16_t*)(ws + ((size_t)22 << 20));  // 8 MB  k [B,H,L,dh]
  uint16_t* vtb = (uint16_t*)(ws + ((size_t)30 << 20));  // 8 MB  v^T perm [B,H,dh,L]

  pack_all<<<7168, 256, 0, stream>>>((const float4*)hidden, hb, Wq, Wk, Wv, Wt);
  qkv_gemm<<<768, 256, 0, stream>>>(hb, Wt, bq, bk, bv, qb, kb, vtb);
  attn<<<1024, 256, 0, stream>>>(qb, kb, vtb, out);
}